// Round 15
// baseline (105.445 us; speedup 1.0000x reference)
//
#include <hip/hip_runtime.h>
#include <hip/hip_bf16.h>
#include <math.h>
#include <stdint.h>

#define N_NODES 100000
#define N_EDGES 1600000
#define IN_DIM 256
#define OUT_DIM 64

#define CWIN  64                          // nodes per window
#define NCB   1563                        // ceil(100000/64)
#define NPART 256                         // 256 * 6250 = 1.6M exact
#define EPP   (N_EDGES / NPART)           // 6250
#define SCAN_N (NCB * NPART)              // 400128
#define SCAN_BLK ((SCAN_N + 4095) / 4096) // 98
#define MAXE  1536                        // window edge cap (mean 1024, ~16 sigma)

#define GEMM_BLKS ((N_NODES + 63) / 64)   // 1563

typedef __attribute__((ext_vector_type(8))) short bh8;   // 8 x bf16 frag
typedef __attribute__((ext_vector_type(4))) float f4;    // mfma accumulator

typedef __attribute__((address_space(1))) const void GV;
typedef __attribute__((address_space(3))) void LV;

// f32 -> bf16 round-to-nearest-even
static __device__ __forceinline__ unsigned short f2bf(float f) {
    unsigned u = __float_as_uint(f);
    unsigned r = (u + 0x7FFFu + ((u >> 16) & 1u)) >> 16;
    return (unsigned short)r;
}

// ---------------------------------------------------------------------------
// Kernel A (MFMA) v5: Wh_bf16 = bf16(h) @ bf16(W).T + fused p_src/p_dst
// + fused coarse histogram (blocks 0..NPART-1).
// Block = 64 nodes, 4 waves; wave = 16 rows x 64 cols.
// KEY CHANGE vs R14: h is staged by global_load_lds (async DMA, no dest
// VGPR -> compiler CANNOT serialize it; R14's VGPR=52 proved reg-prefetch
// was sunk). 2-deep LDS double buffer, 8KB f32 chunk (64 rows x 32 k),
// 2 DMA instructions/wave/chunk, one barrier per chunk.
// Swizzle (rule both-sides): LDS linear; global src slot = (lane&7)^row&7;
// compute reads slot (2g+j)^(row&7)  -> 2-way banks (free).
// LDS = 32KB W + 16KB hbuf = 48KB -> 3 blocks/CU.
// ---------------------------------------------------------------------------
__global__ __launch_bounds__(256) void gat_gemm(
    const float* __restrict__ h, const float* __restrict__ W,
    const float* __restrict__ a, unsigned short* __restrict__ WhB,
    float* __restrict__ p_src, float* __restrict__ p_dst,
    const int* __restrict__ dst, int* __restrict__ cur2dA)
{
    __shared__ __align__(16) unsigned short Wlds[64 * 256];   // 32 KB bf16
    __shared__ __align__(16) float hbuf[2][64 * 32];          // 2 x 8 KB f32

    const int t = threadIdx.x;
    const int lane = t & 63;
    const int wv = t >> 6;
    const int cl = lane & 15;
    const int g  = lane >> 4;
    const int node0 = blockIdx.x * 64;

    // --- h staging addresses (per wave: 2 DMA of 1KB per chunk) ---
    // instruction i covers local rows wv*16 + i*8 + (lane>>3); slot = lane&7.
    const int r0 = wv * 16 + (lane >> 3);          // i=0 row
    const int r1 = r0 + 8;                         // i=1 row
    int gr0 = node0 + r0; gr0 = (gr0 < N_NODES) ? gr0 : N_NODES - 1;
    int gr1 = node0 + r1; gr1 = (gr1 < N_NODES) ? gr1 : N_NODES - 1;
    const int slot0 = (lane & 7) ^ (r0 & 7);       // pre-swizzled global slot
    const int slot1 = (lane & 7) ^ (r1 & 7);
    const float* gsrc0 = h + (size_t)gr0 * IN_DIM + slot0 * 4;
    const float* gsrc1 = h + (size_t)gr1 * IN_DIM + slot1 * 4;

    #define STAGE_H(b, ks)                                                     \
    {                                                                          \
        __builtin_amdgcn_global_load_lds((GV*)(gsrc0 + (ks) * 32),             \
            (LV*)(&hbuf[b][(wv * 16) * 32]), 16, 0, 0);                        \
        __builtin_amdgcn_global_load_lds((GV*)(gsrc1 + (ks) * 32),             \
            (LV*)(&hbuf[b][(wv * 16 + 8) * 32]), 16, 0, 0);                    \
    }

    STAGE_H(0, 0);                                 // chunk 0 in flight

    // --- stage W once (bf16, XOR-swizzled 16B chunks) — overlaps DMA ---
    {
        const int c = t >> 2;
        const int kb = (t & 3) * 8;
        #pragma unroll
        for (int it = 0; it < 8; ++it) {
            const int k16 = kb + it;
            const float4 wlo = *(const float4*)(W + c * IN_DIM + k16 * 8);
            const float4 whi = *(const float4*)(W + c * IN_DIM + k16 * 8 + 4);
            unsigned short tmp[8];
            tmp[0] = f2bf(wlo.x); tmp[1] = f2bf(wlo.y);
            tmp[2] = f2bf(wlo.z); tmp[3] = f2bf(wlo.w);
            tmp[4] = f2bf(whi.x); tmp[5] = f2bf(whi.y);
            tmp[6] = f2bf(whi.z); tmp[7] = f2bf(whi.w);
            const int chunk = c * 32 + (k16 ^ (c & 7));     // XOR swizzle
            *(uint4*)&Wlds[chunk * 8] = *(uint4*)tmp;
        }
    }
    __syncthreads();                               // W + chunk0 complete

    float aS[4], aD[4];
    #pragma unroll
    for (int nt = 0; nt < 4; ++nt) {
        aS[nt] = a[nt * 16 + cl];
        aD[nt] = a[OUT_DIM + nt * 16 + cl];
    }

    f4 acc[4];
    #pragma unroll
    for (int nt = 0; nt < 4; ++nt) acc[nt] = (f4){0.f, 0.f, 0.f, 0.f};

    const int R = wv * 16 + cl;                    // this lane's local row
    const int sA = ((2 * g)     ^ (cl & 7)) * 4;   // swizzled float offsets
    const int sB = ((2 * g + 1) ^ (cl & 7)) * 4;

    int cur = 0;
    #pragma unroll
    for (int ks = 0; ks < 8; ++ks) {
        if (ks < 7) STAGE_H(cur ^ 1, ks + 1);      // prefetch next chunk

        const float4 lo = *(const float4*)&hbuf[cur][R * 32 + sA];
        const float4 hi = *(const float4*)&hbuf[cur][R * 32 + sB];
        bh8 af;
        af[0] = (short)f2bf(lo.x); af[1] = (short)f2bf(lo.y);
        af[2] = (short)f2bf(lo.z); af[3] = (short)f2bf(lo.w);
        af[4] = (short)f2bf(hi.x); af[5] = (short)f2bf(hi.y);
        af[6] = (short)f2bf(hi.z); af[7] = (short)f2bf(hi.w);

        #pragma unroll
        for (int nt = 0; nt < 4; ++nt) {
            const int col = nt * 16 + cl;
            const int k16 = ks * 4 + g;
            const int chunk = col * 32 + (k16 ^ (col & 7));
            const bh8 bf = *(const bh8*)&Wlds[chunk * 8];
            acc[nt] = __builtin_amdgcn_mfma_f32_16x16x32_bf16(af, bf, acc[nt], 0, 0, 0);
        }

        __syncthreads();                           // drain prefetch; buf safe
        cur ^= 1;
    }
    #undef STAGE_H

    // epilogue: Wh (bf16) + p_src/p_dst (f32); C layout row=g*4+r, col=cl
    #pragma unroll
    for (int r = 0; r < 4; ++r) {
        const int orow = node0 + wv * 16 + g * 4 + r;
        float ps = 0.f, pd = 0.f;
        #pragma unroll
        for (int nt = 0; nt < 4; ++nt) {
            ps = fmaf(acc[nt][r], aS[nt], ps);
            pd = fmaf(acc[nt][r], aD[nt], pd);
        }
        #pragma unroll
        for (int o = 8; o > 0; o >>= 1) {
            ps += __shfl_xor(ps, o);
            pd += __shfl_xor(pd, o);
        }
        if (orow < N_NODES) {
            #pragma unroll
            for (int nt = 0; nt < 4; ++nt)
                WhB[(size_t)orow * OUT_DIM + nt * 16 + cl] = f2bf(acc[nt][r]);
            if (cl == 0) { p_src[orow] = ps; p_dst[orow] = pd; }
        }
    }

    // fused coarse histogram: blocks 0..NPART-1, one edge partition each
    if (blockIdx.x < NPART) {
        __syncthreads();                      // Wlds dead -> alias as lh[]
        int* lh = (int*)Wlds;
        for (int i = t; i < NCB; i += 256) lh[i] = 0;
        __syncthreads();
        const int e0 = blockIdx.x * EPP;
        for (int e = e0 + t; e < e0 + EPP; e += 256)
            atomicAdd(&lh[dst[e] >> 6], 1);
        __syncthreads();
        for (int i = t; i < NCB; i += 256)
            cur2dA[i * NPART + blockIdx.x] = lh[i];
    }
}

// ---------------------------------------------------------------------------
// scan1: per-4096-block exclusive scan over cur2dA[400128]; block totals out.
// scan2: exclusive scan of the 98 block totals. (scan3 fused into consumers)
// ---------------------------------------------------------------------------
__global__ __launch_bounds__(1024) void gat_scan1(int* __restrict__ data,
                                                  int* __restrict__ bsum)
{
    __shared__ int ts[1024];
    const int base = blockIdx.x * 4096 + threadIdx.x * 4;
    int v[4];
    #pragma unroll
    for (int j = 0; j < 4; ++j) {
        const int i = base + j;
        v[j] = (i < SCAN_N) ? data[i] : 0;
    }
    const int tsum = v[0] + v[1] + v[2] + v[3];
    ts[threadIdx.x] = tsum;
    __syncthreads();
    int val = tsum;
    for (int s = 1; s < 1024; s <<= 1) {
        const int add = (threadIdx.x >= s) ? ts[threadIdx.x - s] : 0;
        __syncthreads();
        val += add;
        ts[threadIdx.x] = val;
        __syncthreads();
    }
    int run = val - tsum;
    #pragma unroll
    for (int j = 0; j < 4; ++j) {
        const int i = base + j;
        if (i < SCAN_N) data[i] = run;
        run += v[j];
    }
    if (threadIdx.x == 1023) bsum[blockIdx.x] = val;
}

__global__ __launch_bounds__(256) void gat_scan2(int* __restrict__ bsum)
{
    __shared__ int tmp[256];
    const int t = threadIdx.x;
    const int v = (t < SCAN_BLK) ? bsum[t] : 0;
    tmp[t] = v;
    __syncthreads();
    int val = v;
    for (int s = 1; s < 256; s <<= 1) {
        const int add = (t >= s) ? tmp[t - s] : 0;
        __syncthreads();
        val += add;
        tmp[t] = val;
        __syncthreads();
    }
    if (t < SCAN_BLK) bsum[t] = val - v;
}

// ---------------------------------------------------------------------------
// Coarse scatter: per-partition LDS cursors (scan3's bsum add fused here).
// Entry: src | (dst&63)<<17.
// ---------------------------------------------------------------------------
__global__ __launch_bounds__(256) void gat_scatter_coarse(
    const int* __restrict__ src, const int* __restrict__ dst,
    const int* __restrict__ cur2dA, const int* __restrict__ bsum,
    int* __restrict__ ebufA)
{
    __shared__ int lcur[NCB];
    for (int i = threadIdx.x; i < NCB; i += 256) {
        const int idx = i * NPART + blockIdx.x;
        lcur[i] = cur2dA[idx] + bsum[idx >> 12];
    }
    __syncthreads();
    const int e0 = blockIdx.x * EPP;
    for (int e = e0 + threadIdx.x; e < e0 + EPP; e += 256) {
        const int se = src[e], de = dst[e];
        const int pos = atomicAdd(&lcur[de >> 6], 1);
        ebufA[pos] = se | ((de & (CWIN - 1)) << 17);
    }
}

// ---------------------------------------------------------------------------
// Fused node-sort + aggregation (unchanged from R12-R14).
// ---------------------------------------------------------------------------
__global__ __launch_bounds__(256) void gat_agg_fused(
    const int* __restrict__ ebufA, const int* __restrict__ cur2dA,
    const int* __restrict__ bsum,
    const float* __restrict__ p_src, const float* __restrict__ p_dst,
    const unsigned short* __restrict__ Wh, float* __restrict__ out)
{
    __shared__ int2 ledge[MAXE];          // 12 KB: {sv, ex_bits} binned
    __shared__ int lhist[CWIN], lbase[CWIN];
    __shared__ float pdl[CWIN];

    const int t = threadIdx.x;
    const int cb = blockIdx.x;
    const int idx0 = cb * NPART;
    const int a0 = cur2dA[idx0] + bsum[idx0 >> 12];
    int a1 = N_EDGES;
    if (cb < NCB - 1) {
        const int idx1 = (cb + 1) * NPART;
        a1 = cur2dA[idx1] + bsum[idx1 >> 12];
    }
    const int cnt = min(a1 - a0, MAXE);
    const int wbase = cb * CWIN;

    if (t < CWIN) {
        lhist[t] = 0;
        const int node = wbase + t;
        pdl[t] = (node < N_NODES) ? p_dst[node] : 0.f;
    }
    __syncthreads();

    // phase A: coalesced edge read + early p_src gather + hist (rank saved)
    int   ev[6], rk[6];
    float ps[6];
    #pragma unroll
    for (int j = 0; j < 6; ++j) {
        const int i = t + j * 256;
        ev[j] = 0; rk[j] = 0; ps[j] = 0.f;
        if (i < cnt) {
            const int e = ebufA[a0 + i];
            ev[j] = e;
            ps[j] = p_src[e & 0x1FFFF];
            rk[j] = atomicAdd(&lhist[(e >> 17) & (CWIN - 1)], 1);
        }
    }
    __syncthreads();

    // phase B: exclusive scan of 64 bins (wave 0)
    if (t < 64) {
        const int own = lhist[t];
        int val = own;
        #pragma unroll
        for (int s = 1; s < 64; s <<= 1) {
            const int n = __shfl_up(val, s);
            if (t >= s) val += n;
        }
        lbase[t] = val - own;
    }
    __syncthreads();

    // phase C: ex + rank-addressed scatter (no atomics)
    #pragma unroll
    for (int j = 0; j < 6; ++j) {
        const int i = t + j * 256;
        if (i < cnt) {
            const int e = ev[j];
            const int ln = (e >> 17) & (CWIN - 1);
            const float ex = __expf(fmaxf(ps[j] + pdl[ln], 0.f));
            ledge[lbase[ln] + rk[j]] = make_int2(e & 0x1FFFF, __float_as_int(ex));
        }
    }
    __syncthreads();

    // phase D: 16-lane group per node (4 nodes/wave concurrently)
    const int lane = t & 63;
    const int wv = t >> 6;
    const int grp = lane >> 4;
    const int c4 = (lane & 15) * 4;

    #pragma unroll
    for (int rr = 0; rr < 4; ++rr) {
        const int ln = wv * 16 + rr * 4 + grp;
        const int node = wbase + ln;
        const int sb = lbase[ln];
        const int d  = (node < N_NODES) ? lhist[ln] : 0;

        float ssum = 0.f;
        float a0f = 0.f, a1f = 0.f, a2f = 0.f, a3f = 0.f;

        #pragma unroll 4
        for (int k = 0; k < d; ++k) {
            const int2 ed = ledge[sb + k];
            const float ex = __int_as_float(ed.y);
            const uint2 wr = *(const uint2*)(Wh + (size_t)ed.x * OUT_DIM + c4);
            ssum += ex;
            a0f = fmaf(ex, __uint_as_float(wr.x << 16), a0f);
            a1f = fmaf(ex, __uint_as_float(wr.x & 0xFFFF0000u), a1f);
            a2f = fmaf(ex, __uint_as_float(wr.y << 16), a2f);
            a3f = fmaf(ex, __uint_as_float(wr.y & 0xFFFF0000u), a3f);
        }

        if (node < N_NODES) {
            const float inv = (d > 0) ? 1.f / ssum : 0.f;
            float4 ov = make_float4(a0f * inv, a1f * inv, a2f * inv, a3f * inv);
            *(float4*)(out + (size_t)node * OUT_DIM + c4) = ov;
        }
    }
}

// ---------------------------------------------------------------------------
extern "C" void kernel_launch(void* const* d_in, const int* in_sizes, int n_in,
                              void* d_out, int out_size, void* d_ws, size_t ws_size,
                              hipStream_t stream)
{
    const float* h  = (const float*)d_in[0];
    const int* src  = (const int*)d_in[1];
    const int* dst  = (const int*)d_in[2];
    const float* W  = (const float*)d_in[3];
    const float* a  = (const float*)d_in[4];
    float* out = (float*)d_out;

    // workspace layout (bytes), total ~21.6 MB; every buffer write-before-read
    char* ws = (char*)d_ws;
    unsigned short* WhB = (unsigned short*)(ws);      // 12,800,000 (bf16)
    float* p_src   = (float*)(ws + 12800000);         //    400,000
    float* p_dst   = (float*)(ws + 13200000);         //    400,000
    int*   cur2dA  = (int*)  (ws + 13600000);         //  1,600,512 (1563*256)
    int*   bsum    = (int*)  (ws + 15200512);         //        392
    int*   ebufA   = (int*)  (ws + 15200904);         //  6,400,000  (end ~21.6 MB)

    gat_gemm<<<GEMM_BLKS, 256, 0, stream>>>(h, W, a, WhB, p_src,
                                            p_dst, dst, cur2dA);
    gat_scan1<<<SCAN_BLK, 1024, 0, stream>>>(cur2dA, bsum);
    gat_scan2<<<1, 256, 0, stream>>>(bsum);
    gat_scatter_coarse<<<NPART, 256, 0, stream>>>(src, dst, cur2dA, bsum, ebufA);
    gat_agg_fused<<<NCB, 256, 0, stream>>>(ebufA, cur2dA, bsum, p_src, p_dst,
                                           WhB, out);
}